// Round 2
// baseline (31906.982 us; speedup 1.0000x reference)
//
#include <hip/hip_runtime.h>

#define S_LEN 128
#define BATCH 32
#define HID   512
#define GATES 2048      // 4*HID
#define VOCAB 32000
#define NROWS 4096      // S_LEN*BATCH

typedef short bf16x8 __attribute__((ext_vector_type(8)));
typedef float f32x4  __attribute__((ext_vector_type(4)));

__device__ __forceinline__ unsigned short f2bf(float f) {
    unsigned int u = __builtin_bit_cast(unsigned int, f);
    u += 0x7fffu + ((u >> 16) & 1u);            // RNE
    return (unsigned short)(u >> 16);
}
__device__ __forceinline__ float bf2f(unsigned short h) {
    unsigned int u = ((unsigned int)h) << 16;
    return __builtin_bit_cast(float, u);
}
__device__ __forceinline__ float sigmoidf_(float x) { return 1.0f / (1.0f + __expf(-x)); }

// ---------------- embedding gather -> bf16 hi/lo pair ----------------
__global__ __launch_bounds__(256) void embed_k(const int* __restrict__ tokens,
                                               const float* __restrict__ emb,
                                               unsigned short* __restrict__ xhi,
                                               unsigned short* __restrict__ xlo) {
    int gid = blockIdx.x * 256 + threadIdx.x;   // NROWS*128 float4-groups
    int r = gid >> 7, e4 = gid & 127;
    int tok = tokens[r];
    float4 v = ((const float4*)(emb + (size_t)tok * HID))[e4];
    ushort4 hi, lo;
    hi.x = f2bf(v.x); lo.x = f2bf(v.x - bf2f(hi.x));
    hi.y = f2bf(v.y); lo.y = f2bf(v.y - bf2f(hi.y));
    hi.z = f2bf(v.z); lo.z = f2bf(v.z - bf2f(hi.z));
    hi.w = f2bf(v.w); lo.w = f2bf(v.w - bf2f(hi.w));
    ((ushort4*)(xhi + (size_t)r * HID))[e4] = hi;
    ((ushort4*)(xlo + (size_t)r * HID))[e4] = lo;
}

// ---------------- f32 -> bf16 hi(/lo) split ----------------
__global__ __launch_bounds__(256) void f32_split_k(const float* __restrict__ in,
                                                   unsigned short* __restrict__ hi,
                                                   unsigned short* __restrict__ lo, int n4) {
    int i = blockIdx.x * 256 + threadIdx.x;
    if (i >= n4) return;
    float4 v = ((const float4*)in)[i];
    ushort4 h, l;
    h.x = f2bf(v.x); l.x = f2bf(v.x - bf2f(h.x));
    h.y = f2bf(v.y); l.y = f2bf(v.y - bf2f(h.y));
    h.z = f2bf(v.z); l.z = f2bf(v.z - bf2f(h.z));
    h.w = f2bf(v.w); l.w = f2bf(v.w - bf2f(h.w));
    ((ushort4*)hi)[i] = h;
    if (lo) ((ushort4*)lo)[i] = l;
}

// ---------------- split-bf16 MFMA GEMM: C[M,N] = A[M,512] * W[N,512]^T (+bias)
// NPASS=3: hi*hi + hi*lo + lo*hi  (effective f32 precision, ~2^-17 rel err)
// NPASS=1: plain bf16
template<int NPASS>
__global__ __launch_bounds__(256) void gemm_split(const unsigned short* __restrict__ Ahi,
                                                  const unsigned short* __restrict__ Alo,
                                                  const unsigned short* __restrict__ Whi,
                                                  const unsigned short* __restrict__ Wlo,
                                                  const float* __restrict__ bias,
                                                  float* __restrict__ C, int M, int N) {
    const int K = 512;
    __shared__ __align__(16) unsigned short As[128][72];   // +8 pad: 144B stride
    __shared__ __align__(16) unsigned short Bs[128][72];
    int tid = threadIdx.x;
    int n0 = blockIdx.x * 128, m0 = blockIdx.y * 128;
    int wave = tid >> 6, lane = tid & 63;
    int wm = (wave >> 1) * 64, wn = (wave & 1) * 64;
    int lr = lane & 15, kg = lane >> 4;
    f32x4 zero = {0.f, 0.f, 0.f, 0.f};
    f32x4 acc[4][4];
    for (int i = 0; i < 4; ++i)
        for (int j = 0; j < 4; ++j) acc[i][j] = zero;

    const unsigned short* Ap[3] = {Ahi, Ahi, Alo};
    const unsigned short* Wp[3] = {Whi, Wlo, Whi};

    #pragma unroll 1
    for (int p = 0; p < NPASS; ++p) {
        const unsigned short* A = Ap[p];
        const unsigned short* W = Wp[p];
        #pragma unroll 1
        for (int kt = 0; kt < K; kt += 64) {
            uint4 ar[4], br[4];
            #pragma unroll
            for (int q = 0; q < 4; ++q) {
                int c = q * 256 + tid, r = c >> 3, kc = c & 7;
                ar[q] = *(const uint4*)(A + (size_t)(m0 + r) * K + kt + kc * 8);
                br[q] = *(const uint4*)(W + (size_t)(n0 + r) * K + kt + kc * 8);
            }
            __syncthreads();   // previous compute done before overwriting LDS
            #pragma unroll
            for (int q = 0; q < 4; ++q) {
                int c = q * 256 + tid, r = c >> 3, kc = c & 7;
                *(uint4*)&As[r][kc * 8] = ar[q];
                *(uint4*)&Bs[r][kc * 8] = br[q];
            }
            __syncthreads();
            #pragma unroll
            for (int kk = 0; kk < 2; ++kk) {
                bf16x8 af[4], bfr[4];
                #pragma unroll
                for (int i = 0; i < 4; ++i) af[i]  = *(const bf16x8*)&As[wm + i * 16 + lr][kk * 32 + kg * 8];
                #pragma unroll
                for (int j = 0; j < 4; ++j) bfr[j] = *(const bf16x8*)&Bs[wn + j * 16 + lr][kk * 32 + kg * 8];
                #pragma unroll
                for (int i = 0; i < 4; ++i)
                    #pragma unroll
                    for (int j = 0; j < 4; ++j)
                        acc[i][j] = __builtin_amdgcn_mfma_f32_16x16x32_bf16(af[i], bfr[j], acc[i][j], 0, 0, 0);
            }
        }
    }
    // C/D: col = lane&15, row = (lane>>4)*4 + reg
    #pragma unroll
    for (int i = 0; i < 4; ++i) {
        int crow = m0 + wm + i * 16 + kg * 4;
        #pragma unroll
        for (int j = 0; j < 4; ++j) {
            int ccol = n0 + wn + j * 16 + lr;
            float bb = bias ? bias[ccol] : 0.0f;
            #pragma unroll
            for (int r = 0; r < 4; ++r)
                C[(size_t)(crow + r) * N + ccol] = acc[i][j][r] + bb;
        }
    }
}

// ---------------- row LayerNorm in-place: P[4096][2048], apply g,b ----------------
__global__ __launch_bounds__(256) void ln_rows_k(float* __restrict__ P,
                                                 const float* __restrict__ g,
                                                 const float* __restrict__ b) {
    int row = blockIdx.x, tid = threadIdx.x;
    float* p = P + (size_t)row * GATES;
    float4 v0 = ((const float4*)p)[tid];
    float4 v1 = ((const float4*)p)[tid + 256];
    float s  = v0.x + v0.y + v0.z + v0.w + v1.x + v1.y + v1.z + v1.w;
    float sq = v0.x*v0.x + v0.y*v0.y + v0.z*v0.z + v0.w*v0.w
             + v1.x*v1.x + v1.y*v1.y + v1.z*v1.z + v1.w*v1.w;
    __shared__ float rs[256], rq[256];
    rs[tid] = s; rq[tid] = sq; __syncthreads();
    for (int off = 128; off > 0; off >>= 1) {
        if (tid < off) { rs[tid] += rs[tid + off]; rq[tid] += rq[tid + off]; }
        __syncthreads();
    }
    float mean = rs[0] * (1.0f / GATES);
    float var  = rq[0] * (1.0f / GATES) - mean * mean;
    float inv  = rsqrtf(var + 1e-5f);
    float4 g0 = ((const float4*)g)[tid], g1 = ((const float4*)g)[tid + 256];
    float4 b0 = ((const float4*)b)[tid], b1 = ((const float4*)b)[tid + 256];
    float4 o0, o1;
    o0.x = (v0.x - mean) * inv * g0.x + b0.x;
    o0.y = (v0.y - mean) * inv * g0.y + b0.y;
    o0.z = (v0.z - mean) * inv * g0.z + b0.z;
    o0.w = (v0.w - mean) * inv * g0.w + b0.w;
    o1.x = (v1.x - mean) * inv * g1.x + b1.x;
    o1.y = (v1.y - mean) * inv * g1.y + b1.y;
    o1.z = (v1.z - mean) * inv * g1.z + b1.z;
    o1.w = (v1.w - mean) * inv * g1.w + b1.w;
    ((float4*)p)[tid] = o0;
    ((float4*)p)[tid + 256] = o1;
}

// ---------------- one LSTM step (layer-norm LSTM), one WG per batch row ----------------
__global__ __launch_bounds__(256) void lstm_step_k(const float* __restrict__ Whh,   // [2048][512] f32
                                                   const float* __restrict__ gh, const float* __restrict__ bh,
                                                   const float* __restrict__ gc, const float* __restrict__ bc,
                                                   const float* __restrict__ LNi,  // [NROWS][2048]
                                                   float* __restrict__ h_state,    // [B][512]
                                                   float* __restrict__ c_state,    // [B][512]
                                                   unsigned short* __restrict__ hseq_hi,  // [NROWS][512]
                                                   unsigned short* __restrict__ hseq_lo,  // nullable
                                                   int t) {
    __shared__ __align__(16) float hsh[HID];
    __shared__ float zsh[GATES];
    __shared__ float rs[256], rq[256];
    int b = blockIdx.x, tid = threadIdx.x;
    int row = t * BATCH + b;

    for (int u = tid; u < HID; u += 256) hsh[u] = h_state[b * HID + u];
    __syncthreads();

    // z = h @ Whh^T  (8 output gates per thread), pure f32
    float s = 0.f, sq = 0.f;
    const float4* h4 = (const float4*)hsh;
    #pragma unroll
    for (int q = 0; q < 8; ++q) {
        int j = tid + q * 256;
        const float4* wr = (const float4*)(Whh + (size_t)j * HID);
        float a0 = 0.f, a1 = 0.f, a2 = 0.f, a3 = 0.f;
        #pragma unroll 4
        for (int k = 0; k < 128; ++k) {
            float4 w = wr[k], x = h4[k];
            a0 += w.x * x.x; a1 += w.y * x.y; a2 += w.z * x.z; a3 += w.w * x.w;
        }
        float z = (a0 + a1) + (a2 + a3);
        zsh[j] = z; s += z; sq += z * z;
    }
    rs[tid] = s; rq[tid] = sq; __syncthreads();
    for (int off = 128; off > 0; off >>= 1) {
        if (tid < off) { rs[tid] += rs[tid + off]; rq[tid] += rq[tid + off]; }
        __syncthreads();
    }
    float mean = rs[0] * (1.0f / GATES);
    float var  = rq[0] * (1.0f / GATES) - mean * mean;
    float inv  = rsqrtf(var + 1e-5f);
    __syncthreads();   // everyone has read rs/rq before reuse

    const float* lrow = LNi + (size_t)row * GATES;
    float cs = 0.f, cq = 0.f;
    float cnew[2];
    #pragma unroll
    for (int q = 0; q < 2; ++q) {
        int u = tid + q * 256;
        float gi_ = (zsh[u       ] - mean) * inv * gh[u       ] + bh[u       ] + lrow[u       ];
        float gf_ = (zsh[u + 512 ] - mean) * inv * gh[u + 512 ] + bh[u + 512 ] + lrow[u + 512 ];
        float gg_ = (zsh[u + 1024] - mean) * inv * gh[u + 1024] + bh[u + 1024] + lrow[u + 1024];
        float go_ = (zsh[u + 1536] - mean) * inv * gh[u + 1536] + bh[u + 1536] + lrow[u + 1536];
        float c = sigmoidf_(gf_) * c_state[b * HID + u] + sigmoidf_(gi_) * tanhf(gg_);
        cnew[q] = c;
        c_state[b * HID + u] = c;
        zsh[u] = go_;    // stash o-gate; index u only touched by this thread
        cs += c; cq += c * c;
    }
    rs[tid] = cs; rq[tid] = cq; __syncthreads();
    for (int off = 128; off > 0; off >>= 1) {
        if (tid < off) { rs[tid] += rs[tid + off]; rq[tid] += rq[tid + off]; }
        __syncthreads();
    }
    float meanc = rs[0] * (1.0f / HID);
    float varc  = rq[0] * (1.0f / HID) - meanc * meanc;
    float invc  = rsqrtf(varc + 1e-5f);
    #pragma unroll
    for (int q = 0; q < 2; ++q) {
        int u = tid + q * 256;
        float hn = sigmoidf_(zsh[u]) * tanhf((cnew[q] - meanc) * invc * gc[u] + bc[u]);
        h_state[b * HID + u] = hn;
        unsigned short hh = f2bf(hn);
        hseq_hi[(size_t)row * HID + u] = hh;
        if (hseq_lo) hseq_lo[(size_t)row * HID + u] = f2bf(hn - bf2f(hh));
    }
}

// ---------------- in-place log-softmax over V, per row ----------------
__global__ __launch_bounds__(256) void logsoftmax_k(float* __restrict__ out) {
    int row = blockIdx.x, tid = threadIdx.x;
    float* p = out + (size_t)row * VOCAB;
    const float4* p4 = (const float4*)p;
    float m = -3.4e38f, s = 0.f;
    for (int j = tid; j < VOCAB / 4; j += 256) {
        float4 v = p4[j];
        float xs[4] = {v.x, v.y, v.z, v.w};
        #pragma unroll
        for (int e = 0; e < 4; ++e) {
            float x = xs[e];
            if (x > m) { s *= __expf(m - x); m = x; }
            s += __expf(x - m);
        }
    }
    __shared__ float rm[256], rv[256];
    rm[tid] = m; rv[tid] = s; __syncthreads();
    for (int off = 128; off > 0; off >>= 1) {
        if (tid < off) {
            float ma = rm[tid], mb = rm[tid + off];
            float M = fmaxf(ma, mb);
            rv[tid] = rv[tid] * __expf(ma - M) + rv[tid + off] * __expf(mb - M);
            rm[tid] = M;
        }
        __syncthreads();
    }
    float logZ = rm[0] + __logf(rv[0]);
    for (int j = tid; j < VOCAB / 4; j += 256) {
        float4 v = p4[j];
        v.x -= logZ; v.y -= logZ; v.z -= logZ; v.w -= logZ;
        ((float4*)p)[j] = v;
    }
}

// ---------------- copy final states to output tail ----------------
__global__ __launch_bounds__(256) void tail_k(const float* __restrict__ hs,
                                              const float* __restrict__ cs,
                                              float* __restrict__ o) {
    int i = blockIdx.x * 256 + threadIdx.x;    // 65536 total
    o[i] = (i < 32768) ? hs[i] : cs[i - 32768];
}

extern "C" void kernel_launch(void* const* d_in, const int* in_sizes, int n_in,
                              void* d_out, int out_size, void* d_ws, size_t ws_size,
                              hipStream_t stream) {
    const int*   tokens = (const int*)d_in[0];
    const float* emb    = (const float*)d_in[1];
    const float* W_ih   = (const float*)d_in[2];
    const float* W_hh   = (const float*)d_in[3];
    const float* g_ih   = (const float*)d_in[4];
    const float* b_ih   = (const float*)d_in[5];
    const float* g_hh   = (const float*)d_in[6];
    const float* b_hh   = (const float*)d_in[7];
    const float* g_c    = (const float*)d_in[8];
    const float* b_c    = (const float*)d_in[9];
    const float* W_fc   = (const float*)d_in[10];
    const float* b_fc   = (const float*)d_in[11];
    float* out = (float*)d_out;

    char* ws = (char*)d_ws;
    // workspace layout (bytes)
    unsigned short* XembHi  = (unsigned short*)(ws + 0);               //  4 MB
    unsigned short* XembLo  = (unsigned short*)(ws + ( 4ull << 20));   //  4 MB
    unsigned short* hseq0Hi = (unsigned short*)(ws + ( 8ull << 20));   //  4 MB
    unsigned short* hseq0Lo = (unsigned short*)(ws + (12ull << 20));   //  4 MB
    unsigned short* hseq1Hi = (unsigned short*)(ws + (16ull << 20));   //  4 MB
    unsigned short* WihHi   = (unsigned short*)(ws + (20ull << 20));   //  2 MB
    unsigned short* WihLo   = (unsigned short*)(ws + (22ull << 20));   //  2 MB
    unsigned short* WfcHi   = (unsigned short*)(ws + (24ull << 20));   // 32.8 MB
    float*          P       = (float*)(ws + (58ull << 20));            // 32 MB
    float*          hstate  = (float*)(ws + (90ull << 20));            // 256 KB (h then c)
    float*          cstate  = (float*)(ws + (90ull << 20) + 262144);

    embed_k<<<2048, 256, 0, stream>>>(tokens, emb, XembHi, XembLo);

    const unsigned short* xhi[2] = {XembHi, hseq0Hi};
    const unsigned short* xlo[2] = {XembLo, hseq0Lo};
    unsigned short* hhi[2] = {hseq0Hi, hseq1Hi};
    unsigned short* hlo[2] = {hseq0Lo, nullptr};

    for (int l = 0; l < 2; ++l) {
        f32_split_k<<<1024, 256, 0, stream>>>(W_ih + (size_t)l * GATES * HID, WihHi, WihLo, GATES * HID / 4);
        gemm_split<3><<<dim3(GATES / 128, NROWS / 128), 256, 0, stream>>>(
            xhi[l], xlo[l], WihHi, WihLo, nullptr, P, NROWS, GATES);
        ln_rows_k<<<NROWS, 256, 0, stream>>>(P, g_ih + l * GATES, b_ih + l * GATES);
        hipMemsetAsync(hstate + (size_t)l * BATCH * HID, 0, BATCH * HID * sizeof(float), stream);
        hipMemsetAsync(cstate + (size_t)l * BATCH * HID, 0, BATCH * HID * sizeof(float), stream);
        for (int t = 0; t < S_LEN; ++t) {
            lstm_step_k<<<BATCH, 256, 0, stream>>>(W_hh + (size_t)l * GATES * HID,
                                                   g_hh + l * GATES, b_hh + l * GATES,
                                                   g_c + l * HID, b_c + l * HID,
                                                   P,
                                                   hstate + (size_t)l * BATCH * HID,
                                                   cstate + (size_t)l * BATCH * HID,
                                                   hhi[l], hlo[l], t);
        }
    }

    f32_split_k<<<16000, 256, 0, stream>>>(W_fc, WfcHi, nullptr, VOCAB * HID / 4);
    gemm_split<1><<<dim3(VOCAB / 128, NROWS / 128), 256, 0, stream>>>(
        hseq1Hi, nullptr, WfcHi, nullptr, b_fc, out, NROWS, VOCAB);
    logsoftmax_k<<<NROWS, 256, 0, stream>>>(out);
    tail_k<<<256, 256, 0, stream>>>(hstate, cstate, out + (size_t)NROWS * VOCAB);
}

// Round 4
// 7419.972 us; speedup vs baseline: 4.3001x; 4.3001x over previous
//
#include <hip/hip_runtime.h>

#define S_LEN 128
#define BATCH 32
#define HID   512
#define GATES 2048      // 4*HID
#define VOCAB 32000
#define NROWS 4096      // S_LEN*BATCH
#define NWG   64        // persistent WGs
#define WROWS 32        // gate rows per WG

typedef short bf16x8 __attribute__((ext_vector_type(8)));
typedef float f32x4  __attribute__((ext_vector_type(4)));

__device__ __forceinline__ unsigned short f2bf(float f) {
    unsigned int u = __builtin_bit_cast(unsigned int, f);
    u += 0x7fffu + ((u >> 16) & 1u);            // RNE
    return (unsigned short)(u >> 16);
}
__device__ __forceinline__ float bf2f(unsigned short h) {
    unsigned int u = ((unsigned int)h) << 16;
    return __builtin_bit_cast(float, u);
}
__device__ __forceinline__ float sigmoidf_(float x) { return 1.0f / (1.0f + __expf(-x)); }

// ---------------- embedding gather -> bf16 hi/lo pair ----------------
__global__ __launch_bounds__(256) void embed_k(const int* __restrict__ tokens,
                                               const float* __restrict__ emb,
                                               unsigned short* __restrict__ xhi,
                                               unsigned short* __restrict__ xlo) {
    int gid = blockIdx.x * 256 + threadIdx.x;   // NROWS*128 float4-groups
    int r = gid >> 7, e4 = gid & 127;
    int tok = tokens[r];
    float4 v = ((const float4*)(emb + (size_t)tok * HID))[e4];
    ushort4 hi, lo;
    hi.x = f2bf(v.x); lo.x = f2bf(v.x - bf2f(hi.x));
    hi.y = f2bf(v.y); lo.y = f2bf(v.y - bf2f(hi.y));
    hi.z = f2bf(v.z); lo.z = f2bf(v.z - bf2f(hi.z));
    hi.w = f2bf(v.w); lo.w = f2bf(v.w - bf2f(hi.w));
    ((ushort4*)(xhi + (size_t)r * HID))[e4] = hi;
    ((ushort4*)(xlo + (size_t)r * HID))[e4] = lo;
}

// ---------------- f32 -> bf16 hi(/lo) split ----------------
__global__ __launch_bounds__(256) void f32_split_k(const float* __restrict__ in,
                                                   unsigned short* __restrict__ hi,
                                                   unsigned short* __restrict__ lo, int n4) {
    int i = blockIdx.x * 256 + threadIdx.x;
    if (i >= n4) return;
    float4 v = ((const float4*)in)[i];
    ushort4 h, l;
    h.x = f2bf(v.x); l.x = f2bf(v.x - bf2f(h.x));
    h.y = f2bf(v.y); l.y = f2bf(v.y - bf2f(h.y));
    h.z = f2bf(v.z); l.z = f2bf(v.z - bf2f(h.z));
    h.w = f2bf(v.w); l.w = f2bf(v.w - bf2f(h.w));
    ((ushort4*)hi)[i] = h;
    if (lo) ((ushort4*)lo)[i] = l;
}

// ---------------- split-bf16 MFMA GEMM: C[M,N] = A[M,512] * W[N,512]^T (+bias) ----------------
template<int NPASS>
__global__ __launch_bounds__(256) void gemm_split(const unsigned short* __restrict__ Ahi,
                                                  const unsigned short* __restrict__ Alo,
                                                  const unsigned short* __restrict__ Whi,
                                                  const unsigned short* __restrict__ Wlo,
                                                  const float* __restrict__ bias,
                                                  float* __restrict__ C, int M, int N) {
    const int K = 512;
    __shared__ __align__(16) unsigned short As[128][72];   // +8 pad: 144B stride
    __shared__ __align__(16) unsigned short Bs[128][72];
    int tid = threadIdx.x;
    int n0 = blockIdx.x * 128, m0 = blockIdx.y * 128;
    int wave = tid >> 6, lane = tid & 63;
    int wm = (wave >> 1) * 64, wn = (wave & 1) * 64;
    int lr = lane & 15, kg = lane >> 4;
    f32x4 zero = {0.f, 0.f, 0.f, 0.f};
    f32x4 acc[4][4];
    for (int i = 0; i < 4; ++i)
        for (int j = 0; j < 4; ++j) acc[i][j] = zero;

    const unsigned short* Ap[3] = {Ahi, Ahi, Alo};
    const unsigned short* Wp[3] = {Whi, Wlo, Whi};

    #pragma unroll 1
    for (int p = 0; p < NPASS; ++p) {
        const unsigned short* A = Ap[p];
        const unsigned short* W = Wp[p];
        #pragma unroll 1
        for (int kt = 0; kt < K; kt += 64) {
            uint4 ar[4], br[4];
            #pragma unroll
            for (int q = 0; q < 4; ++q) {
                int c = q * 256 + tid, r = c >> 3, kc = c & 7;
                ar[q] = *(const uint4*)(A + (size_t)(m0 + r) * K + kt + kc * 8);
                br[q] = *(const uint4*)(W + (size_t)(n0 + r) * K + kt + kc * 8);
            }
            __syncthreads();
            #pragma unroll
            for (int q = 0; q < 4; ++q) {
                int c = q * 256 + tid, r = c >> 3, kc = c & 7;
                *(uint4*)&As[r][kc * 8] = ar[q];
                *(uint4*)&Bs[r][kc * 8] = br[q];
            }
            __syncthreads();
            #pragma unroll
            for (int kk = 0; kk < 2; ++kk) {
                bf16x8 af[4], bfr[4];
                #pragma unroll
                for (int i = 0; i < 4; ++i) af[i]  = *(const bf16x8*)&As[wm + i * 16 + lr][kk * 32 + kg * 8];
                #pragma unroll
                for (int j = 0; j < 4; ++j) bfr[j] = *(const bf16x8*)&Bs[wn + j * 16 + lr][kk * 32 + kg * 8];
                #pragma unroll
                for (int i = 0; i < 4; ++i)
                    #pragma unroll
                    for (int j = 0; j < 4; ++j)
                        acc[i][j] = __builtin_amdgcn_mfma_f32_16x16x32_bf16(af[i], bfr[j], acc[i][j], 0, 0, 0);
            }
        }
    }
    #pragma unroll
    for (int i = 0; i < 4; ++i) {
        int crow = m0 + wm + i * 16 + kg * 4;
        #pragma unroll
        for (int j = 0; j < 4; ++j) {
            int ccol = n0 + wn + j * 16 + lr;
            float bb = bias ? bias[ccol] : 0.0f;
            #pragma unroll
            for (int r = 0; r < 4; ++r)
                C[(size_t)(crow + r) * N + ccol] = acc[i][j][r] + bb;
        }
    }
}

// ---------------- row LayerNorm in-place: P[4096][2048], apply g,b ----------------
__global__ __launch_bounds__(256) void ln_rows_k(float* __restrict__ P,
                                                 const float* __restrict__ g,
                                                 const float* __restrict__ b) {
    int row = blockIdx.x, tid = threadIdx.x;
    float* p = P + (size_t)row * GATES;
    float4 v0 = ((const float4*)p)[tid];
    float4 v1 = ((const float4*)p)[tid + 256];
    float s  = v0.x + v0.y + v0.z + v0.w + v1.x + v1.y + v1.z + v1.w;
    float sq = v0.x*v0.x + v0.y*v0.y + v0.z*v0.z + v0.w*v0.w
             + v1.x*v1.x + v1.y*v1.y + v1.z*v1.z + v1.w*v1.w;
    __shared__ float rs[256], rq[256];
    rs[tid] = s; rq[tid] = sq; __syncthreads();
    for (int off = 128; off > 0; off >>= 1) {
        if (tid < off) { rs[tid] += rs[tid + off]; rq[tid] += rq[tid + off]; }
        __syncthreads();
    }
    float mean = rs[0] * (1.0f / GATES);
    float var  = rq[0] * (1.0f / GATES) - mean * mean;
    float inv  = rsqrtf(var + 1e-5f);
    float4 g0 = ((const float4*)g)[tid], g1 = ((const float4*)g)[tid + 256];
    float4 b0 = ((const float4*)b)[tid], b1 = ((const float4*)b)[tid + 256];
    float4 o0, o1;
    o0.x = (v0.x - mean) * inv * g0.x + b0.x;
    o0.y = (v0.y - mean) * inv * g0.y + b0.y;
    o0.z = (v0.z - mean) * inv * g0.z + b0.z;
    o0.w = (v0.w - mean) * inv * g0.w + b0.w;
    o1.x = (v1.x - mean) * inv * g1.x + b1.x;
    o1.y = (v1.y - mean) * inv * g1.y + b1.y;
    o1.z = (v1.z - mean) * inv * g1.z + b1.z;
    o1.w = (v1.w - mean) * inv * g1.w + b1.w;
    ((float4*)p)[tid] = o0;
    ((float4*)p)[tid + 256] = o1;
}

// ---------------- device-scope barrier ----------------
__device__ __forceinline__ void grid_barrier(unsigned* counter, unsigned* gen, int nwg) {
    __syncthreads();                      // drains vmcnt: WG stores are in L2
    if (threadIdx.x == 0) {
        __threadfence();                  // release
        unsigned g = __hip_atomic_load(gen, __ATOMIC_RELAXED, __HIP_MEMORY_SCOPE_AGENT);
        unsigned prev = __hip_atomic_fetch_add(counter, 1u, __ATOMIC_ACQ_REL, __HIP_MEMORY_SCOPE_AGENT);
        if (prev == (unsigned)(nwg - 1)) {
            __hip_atomic_store(counter, 0u, __ATOMIC_RELAXED, __HIP_MEMORY_SCOPE_AGENT);
            __hip_atomic_store(gen, g + 1u, __ATOMIC_RELEASE, __HIP_MEMORY_SCOPE_AGENT);
        } else {
            while (__hip_atomic_load(gen, __ATOMIC_ACQUIRE, __HIP_MEMORY_SCOPE_AGENT) == g) {
                __builtin_amdgcn_s_sleep(2);
            }
        }
        __threadfence();                  // acquire
    }
    __syncthreads();
}

// ---------------- persistent LayerNorm-LSTM recurrence (one layer, all 128 steps)
// 64 WGs x 256 threads. WG w: phase A owns gate rows [w*32,w*32+32) as 3-term bf16 in LDS;
// phase B (w<32) owns batch element w (c-state in LDS). 6-pass split-MFMA z == f32 precision.
__global__ __launch_bounds__(256, 1) void lstm_persist_k(
        const float* __restrict__ Whh,       // [2048][512] (layer slice, f32)
        const float* __restrict__ gh, const float* __restrict__ bh,
        const float* __restrict__ gc, const float* __restrict__ bc,
        const float* __restrict__ LNi,       // [4096][2048] precomputed LN(x@Wi^T)
        unsigned short* __restrict__ hHi,    // [32][512] 3-term bf16 h state (init 0)
        unsigned short* __restrict__ hMid,
        unsigned short* __restrict__ hLo,
        float* __restrict__ zbuf,            // [32][2048]
        float* __restrict__ pstats,          // [64 wg][32 b][2]
        unsigned* __restrict__ bar,          // {counter, gen}
        unsigned short* __restrict__ seqHi,  // [4096][512]
        unsigned short* __restrict__ seqLo,  // nullable
        float* __restrict__ outH,            // [32][512] final h (f32)
        float* __restrict__ outC) {          // [32][512] final c (f32)
    __shared__ __align__(16) unsigned short Wlds[3][WROWS * HID];  // 96 KB
    __shared__ float ghs[GATES], bhs[GATES];                       // 16 KB
    __shared__ float gcs[HID], bcs[HID];                           // 4 KB
    __shared__ float c_lds[HID];                                   // 2 KB
    __shared__ float pstatA[2][BATCH][2];
    __shared__ float sred[2];
    __shared__ float cred[4][2];

    const int w = blockIdx.x;
    const int tid = threadIdx.x;
    const int wave = tid >> 6, lane = tid & 63;
    const int lr = lane & 15, kg = lane >> 4;
    const int mr = wave >> 1, nc = wave & 1;

    for (int u = tid; u < GATES; u += 256) { ghs[u] = gh[u]; bhs[u] = bh[u]; }
    for (int u = tid; u < HID;   u += 256) { gcs[u] = gc[u]; bcs[u] = bc[u]; c_lds[u] = 0.f; }

    // ---- stage Whh rows [w*32, w*32+32) -> 3-term bf16, XOR-swizzled 16B chunks ----
    #pragma unroll
    for (int i = 0; i < 8; ++i) {
        int chunk = tid + i * 256;            // 0..2047 : row r (0..31), 8-elem chunk c8 (0..63)
        int r = chunk >> 6, c8 = chunk & 63;
        const float* src = Whh + (size_t)(w * WROWS + r) * HID + c8 * 8;
        float4 v0 = *(const float4*)(src);
        float4 v1 = *(const float4*)(src + 4);
        float f[8] = {v0.x, v0.y, v0.z, v0.w, v1.x, v1.y, v1.z, v1.w};
        bf16x8 t0, t1, t2;
        #pragma unroll
        for (int e = 0; e < 8; ++e) {
            unsigned short h0 = f2bf(f[e]);
            float r1 = f[e] - bf2f(h0);
            unsigned short h1 = f2bf(r1);
            float r2 = r1 - bf2f(h1);
            t0[e] = (short)h0; t1[e] = (short)h1; t2[e] = (short)f2bf(r2);
        }
        int eoff = r * HID + ((c8 * 8) ^ ((r & 7) * 8));
        *(bf16x8*)&Wlds[0][eoff] = t0;
        *(bf16x8*)&Wlds[1][eoff] = t1;
        *(bf16x8*)&Wlds[2][eoff] = t2;
    }
    __syncthreads();

    const int arow = (mr * 16 + lr) * HID;
    const int wrow = (nc * 16 + lr) * HID;
    const int sw = (lr & 7) * 8;

    for (int t = 0; t < S_LEN; ++t) {
        // ===== Phase A: z[b][w*32+j] = h @ W_slice^T, 6-pass 3-term split bf16 =====
        f32x4 zero = {0.f, 0.f, 0.f, 0.f};
        f32x4 acc[4] = {zero, zero, zero, zero};
#define PASS(HA, TERM)                                                                   \
        { _Pragma("unroll")                                                              \
          for (int kk = 0; kk < 16; ++kk) {                                              \
              bf16x8 af = *(const bf16x8*)((HA) + arow + kk * 32 + kg * 8);              \
              bf16x8 bv = *(const bf16x8*)&Wlds[TERM][wrow + ((kk * 32 + kg * 8) ^ sw)]; \
              acc[kk & 3] = __builtin_amdgcn_mfma_f32_16x16x32_bf16(af, bv, acc[kk & 3], 0, 0, 0); \
          } }
        PASS(hHi, 0)   // hi*Whi
        PASS(hHi, 1)   // hi*Wmid
        PASS(hMid, 0)  // mid*Whi
        PASS(hMid, 1)  // mid*Wmid
        PASS(hLo, 0)   // lo*Whi
        PASS(hHi, 2)   // hi*Wlo
#undef PASS
        f32x4 a = acc[0] + acc[1] + acc[2] + acc[3];

        float sv[4], qv[4];
        #pragma unroll
        for (int r = 0; r < 4; ++r) {
            int b = mr * 16 + kg * 4 + r;
            int col = w * WROWS + nc * 16 + lr;
            zbuf[b * GATES + col] = a[r];
            sv[r] = a[r]; qv[r] = a[r] * a[r];
        }
        #pragma unroll
        for (int m = 1; m <= 8; m <<= 1) {
            #pragma unroll
            for (int r = 0; r < 4; ++r) {
                sv[r] += __shfl_xor(sv[r], m);
                qv[r] += __shfl_xor(qv[r], m);
            }
        }
        if (lr == 0) {
            #pragma unroll
            for (int r = 0; r < 4; ++r) {
                int b = mr * 16 + kg * 4 + r;
                pstatA[nc][b][0] = sv[r];
                pstatA[nc][b][1] = qv[r];
            }
        }
        __syncthreads();
        if (tid < 64) {
            int b = tid & 31, s = tid >> 5;
            pstats[(w * BATCH + b) * 2 + s] = pstatA[0][b][s] + pstatA[1][b][s];
        }
        grid_barrier(&bar[0], &bar[1], NWG);   // barrier 1: z + stats visible

        // ===== Phase B: batch element g = w (first 32 WGs) =====
        if (w < BATCH) {
            const int g = w;
            const int row = t * BATCH + g;
            if (tid < 128) {
                int s = tid >> 6, ww = tid & 63;
                float v = pstats[(ww * BATCH + g) * 2 + s];
                #pragma unroll
                for (int m = 1; m <= 32; m <<= 1) v += __shfl_xor(v, m);
                if ((tid & 63) == 0) sred[s] = v;
            }
            __syncthreads();
            float mean = sred[0] * (1.0f / GATES);
            float var  = sred[1] * (1.0f / GATES) - mean * mean;
            float inv  = rsqrtf(var + 1e-5f);

            const float* lrow = LNi + (size_t)row * GATES;
            const float* zrow = zbuf + g * GATES;
            float cvals[2], ovals[2];
            float cs = 0.f, cq = 0.f;
            #pragma unroll
            for (int q = 0; q < 2; ++q) {
                int u = tid + q * 256;
                float gi_ = (zrow[u       ] - mean) * inv * ghs[u       ] + bhs[u       ] + lrow[u       ];
                float gf_ = (zrow[u + 512 ] - mean) * inv * ghs[u + 512 ] + bhs[u + 512 ] + lrow[u + 512 ];
                float gg_ = (zrow[u + 1024] - mean) * inv * ghs[u + 1024] + bhs[u + 1024] + lrow[u + 1024];
                float go_ = (zrow[u + 1536] - mean) * inv * ghs[u + 1536] + bhs[u + 1536] + lrow[u + 1536];
                float c = sigmoidf_(gf_) * c_lds[u] + sigmoidf_(gi_) * tanhf(gg_);
                c_lds[u] = c;
                cvals[q] = c; ovals[q] = go_;
                cs += c; cq += c * c;
            }
            #pragma unroll
            for (int m = 1; m < 64; m <<= 1) { cs += __shfl_xor(cs, m); cq += __shfl_xor(cq, m); }
            if (lane == 0) { cred[wave][0] = cs; cred[wave][1] = cq; }
            __syncthreads();
            float csum = cred[0][0] + cred[1][0] + cred[2][0] + cred[3][0];
            float cqsum = cred[0][1] + cred[1][1] + cred[2][1] + cred[3][1];
            float meanc = csum * (1.0f / HID);
            float varc  = cqsum * (1.0f / HID) - meanc * meanc;
            float invc  = rsqrtf(varc + 1e-5f);
            #pragma unroll
            for (int q = 0; q < 2; ++q) {
                int u = tid + q * 256;
                float h = sigmoidf_(ovals[q]) * tanhf((cvals[q] - meanc) * invc * gcs[u] + bcs[u]);
                unsigned short h0 = f2bf(h);
                float r1 = h - bf2f(h0);
                unsigned short h1 = f2bf(r1);
                unsigned short h2 = f2bf(r1 - bf2f(h1));
                hHi [g * HID + u] = h0;
                hMid[g * HID + u] = h1;
                hLo [g * HID + u] = h2;
                seqHi[(size_t)row * HID + u] = h0;
                if (seqLo) seqLo[(size_t)row * HID + u] = h1;
                if (t == S_LEN - 1) { outH[g * HID + u] = h; outC[g * HID + u] = cvals[q]; }
            }
        }
        if (t < S_LEN - 1) grid_barrier(&bar[0], &bar[1], NWG);   // barrier 2: h visible
    }
}

// ---------------- in-place log-softmax over V, per row ----------------
__global__ __launch_bounds__(256) void logsoftmax_k(float* __restrict__ out) {
    int row = blockIdx.x, tid = threadIdx.x;
    float* p = out + (size_t)row * VOCAB;
    const float4* p4 = (const float4*)p;
    float m = -3.4e38f, s = 0.f;
    for (int j = tid; j < VOCAB / 4; j += 256) {
        float4 v = p4[j];
        float xs[4] = {v.x, v.y, v.z, v.w};
        #pragma unroll
        for (int e = 0; e < 4; ++e) {
            float x = xs[e];
            if (x > m) { s *= __expf(m - x); m = x; }
            s += __expf(x - m);
        }
    }
    __shared__ float rm[256], rv[256];
    rm[tid] = m; rv[tid] = s; __syncthreads();
    for (int off = 128; off > 0; off >>= 1) {
        if (tid < off) {
            float ma = rm[tid], mb = rm[tid + off];
            float M = fmaxf(ma, mb);
            rv[tid] = rv[tid] * __expf(ma - M) + rv[tid + off] * __expf(mb - M);
            rm[tid] = M;
        }
        __syncthreads();
    }
    float logZ = rm[0] + __logf(rv[0]);
    for (int j = tid; j < VOCAB / 4; j += 256) {
        float4 v = p4[j];
        v.x -= logZ; v.y -= logZ; v.z -= logZ; v.w -= logZ;
        ((float4*)p)[j] = v;
    }
}

extern "C" void kernel_launch(void* const* d_in, const int* in_sizes, int n_in,
                              void* d_out, int out_size, void* d_ws, size_t ws_size,
                              hipStream_t stream) {
    const int*   tokens = (const int*)d_in[0];
    const float* emb    = (const float*)d_in[1];
    const float* W_ih   = (const float*)d_in[2];
    const float* W_hh   = (const float*)d_in[3];
    const float* g_ih   = (const float*)d_in[4];
    const float* b_ih   = (const float*)d_in[5];
    const float* g_hh   = (const float*)d_in[6];
    const float* b_hh   = (const float*)d_in[7];
    const float* g_c    = (const float*)d_in[8];
    const float* b_c    = (const float*)d_in[9];
    const float* W_fc   = (const float*)d_in[10];
    const float* b_fc   = (const float*)d_in[11];
    float* out = (float*)d_out;

    char* ws = (char*)d_ws;
    unsigned short* XembHi  = (unsigned short*)(ws + 0);               //  4 MB
    unsigned short* XembLo  = (unsigned short*)(ws + ( 4ull << 20));   //  4 MB
    unsigned short* hseq0Hi = (unsigned short*)(ws + ( 8ull << 20));   //  4 MB
    unsigned short* hseq0Lo = (unsigned short*)(ws + (12ull << 20));   //  4 MB
    unsigned short* hseq1Hi = (unsigned short*)(ws + (16ull << 20));   //  4 MB
    unsigned short* WihHi   = (unsigned short*)(ws + (20ull << 20));   //  2 MB
    unsigned short* WihLo   = (unsigned short*)(ws + (22ull << 20));   //  2 MB
    unsigned short* WfcHi   = (unsigned short*)(ws + (24ull << 20));   // 32.8 MB
    float*          P       = (float*)(ws + (58ull << 20));            // 32 MB
    char*           xtra    = ws + (90ull << 20);
    float*          zbuf    = (float*)(xtra);                          // 256 KB
    float*          pstats  = (float*)(xtra + 262144);                 // 16 KB
    unsigned short* hHi     = (unsigned short*)(xtra + 262144 + 16384);            // 32 KB
    unsigned short* hMid    = (unsigned short*)(xtra + 262144 + 16384 + 32768);    // 32 KB
    unsigned short* hLo     = (unsigned short*)(xtra + 262144 + 16384 + 65536);    // 32 KB
    unsigned*       bar     = (unsigned*)(xtra + 262144 + 16384 + 98304);          // 8 B

    float* tail = out + (size_t)NROWS * VOCAB;   // h_n [2][32][512] then c_n [2][32][512]

    hipMemsetAsync(bar, 0, 2 * sizeof(unsigned), stream);
    embed_k<<<2048, 256, 0, stream>>>(tokens, emb, XembHi, XembLo);

    const unsigned short* xhi[2] = {XembHi, hseq0Hi};
    const unsigned short* xlo[2] = {XembLo, hseq0Lo};
    unsigned short* shi[2] = {hseq0Hi, hseq1Hi};
    unsigned short* slo[2] = {hseq0Lo, nullptr};

    for (int l = 0; l < 2; ++l) {
        f32_split_k<<<1024, 256, 0, stream>>>(W_ih + (size_t)l * GATES * HID, WihHi, WihLo, GATES * HID / 4);
        gemm_split<3><<<dim3(GATES / 128, NROWS / 128), 256, 0, stream>>>(
            xhi[l], xlo[l], WihHi, WihLo, nullptr, P, NROWS, GATES);
        ln_rows_k<<<NROWS, 256, 0, stream>>>(P, g_ih + l * GATES, b_ih + l * GATES);
        hipMemsetAsync(hHi,  0, BATCH * HID * sizeof(unsigned short), stream);
        hipMemsetAsync(hMid, 0, BATCH * HID * sizeof(unsigned short), stream);
        hipMemsetAsync(hLo,  0, BATCH * HID * sizeof(unsigned short), stream);
        lstm_persist_k<<<NWG, 256, 0, stream>>>(
            W_hh + (size_t)l * GATES * HID,
            g_hh + l * GATES, b_hh + l * GATES,
            g_c + l * HID, b_c + l * HID,
            P, hHi, hMid, hLo, zbuf, pstats, bar,
            shi[l], slo[l],
            tail + l * BATCH * HID,
            tail + 2 * BATCH * HID + l * BATCH * HID);
    }

    f32_split_k<<<16000, 256, 0, stream>>>(W_fc, WfcHi, nullptr, VOCAB * HID / 4);
    gemm_split<1><<<dim3(VOCAB / 128, NROWS / 128), 256, 0, stream>>>(
        hseq1Hi, nullptr, WfcHi, nullptr, b_fc, out, NROWS, VOCAB);
    logsoftmax_k<<<NROWS, 256, 0, stream>>>(out);
}

// Round 5
// 4401.957 us; speedup vs baseline: 7.2484x; 1.6856x over previous
//
#include <hip/hip_runtime.h>

#define S_LEN 128
#define BATCH 32
#define HID   512
#define GATES 2048      // 4*HID
#define VOCAB 32000
#define NROWS 4096      // S_LEN*BATCH
#define NWG   64        // persistent WGs
#define WROWS 32        // gate rows per WG

typedef short bf16x8 __attribute__((ext_vector_type(8)));
typedef float f32x4  __attribute__((ext_vector_type(4)));

__device__ __forceinline__ unsigned short f2bf(float f) {
    unsigned int u = __builtin_bit_cast(unsigned int, f);
    u += 0x7fffu + ((u >> 16) & 1u);            // RNE
    return (unsigned short)(u >> 16);
}
__device__ __forceinline__ float bf2f(unsigned short h) {
    unsigned int u = ((unsigned int)h) << 16;
    return __builtin_bit_cast(float, u);
}
__device__ __forceinline__ float sigmoidf_(float x) { return 1.0f / (1.0f + __expf(-x)); }

// ---- coherent (LLC-level, cross-XCD) memory ops: bypass non-coherent per-XCD L2 ----
__device__ __forceinline__ void st_coh_f32(void* p, float v) {
    asm volatile("global_store_dword %0, %1, off sc0 sc1" :: "v"(p), "v"(v) : "memory");
}
__device__ __forceinline__ void st_coh_u32(void* p, unsigned v) {
    asm volatile("global_store_dword %0, %1, off sc0 sc1" :: "v"(p), "v"(v) : "memory");
}
__device__ __forceinline__ void st_coh_u16(void* p, unsigned v) {
    asm volatile("global_store_short %0, %1, off sc0 sc1" :: "v"(p), "v"(v) : "memory");
}

// ---------------- embedding gather -> bf16 hi/lo pair ----------------
__global__ __launch_bounds__(256) void embed_k(const int* __restrict__ tokens,
                                               const float* __restrict__ emb,
                                               unsigned short* __restrict__ xhi,
                                               unsigned short* __restrict__ xlo) {
    int gid = blockIdx.x * 256 + threadIdx.x;   // NROWS*128 float4-groups
    int r = gid >> 7, e4 = gid & 127;
    int tok = tokens[r];
    float4 v = ((const float4*)(emb + (size_t)tok * HID))[e4];
    ushort4 hi, lo;
    hi.x = f2bf(v.x); lo.x = f2bf(v.x - bf2f(hi.x));
    hi.y = f2bf(v.y); lo.y = f2bf(v.y - bf2f(hi.y));
    hi.z = f2bf(v.z); lo.z = f2bf(v.z - bf2f(hi.z));
    hi.w = f2bf(v.w); lo.w = f2bf(v.w - bf2f(hi.w));
    ((ushort4*)(xhi + (size_t)r * HID))[e4] = hi;
    ((ushort4*)(xlo + (size_t)r * HID))[e4] = lo;
}

// ---------------- f32 -> bf16 hi(/lo) split ----------------
__global__ __launch_bounds__(256) void f32_split_k(const float* __restrict__ in,
                                                   unsigned short* __restrict__ hi,
                                                   unsigned short* __restrict__ lo, int n4) {
    int i = blockIdx.x * 256 + threadIdx.x;
    if (i >= n4) return;
    float4 v = ((const float4*)in)[i];
    ushort4 h, l;
    h.x = f2bf(v.x); l.x = f2bf(v.x - bf2f(h.x));
    h.y = f2bf(v.y); l.y = f2bf(v.y - bf2f(h.y));
    h.z = f2bf(v.z); l.z = f2bf(v.z - bf2f(h.z));
    h.w = f2bf(v.w); l.w = f2bf(v.w - bf2f(h.w));
    ((ushort4*)hi)[i] = h;
    if (lo) ((ushort4*)lo)[i] = l;
}

// ---------------- split-bf16 MFMA GEMM: C[M,N] = A[M,512] * W[N,512]^T (+bias) ----------------
template<int NPASS>
__global__ __launch_bounds__(256) void gemm_split(const unsigned short* __restrict__ Ahi,
                                                  const unsigned short* __restrict__ Alo,
                                                  const unsigned short* __restrict__ Whi,
                                                  const unsigned short* __restrict__ Wlo,
                                                  const float* __restrict__ bias,
                                                  float* __restrict__ C, int M, int N) {
    const int K = 512;
    __shared__ __align__(16) unsigned short As[128][72];   // +8 pad: 144B stride
    __shared__ __align__(16) unsigned short Bs[128][72];
    int tid = threadIdx.x;
    int n0 = blockIdx.x * 128, m0 = blockIdx.y * 128;
    int wave = tid >> 6, lane = tid & 63;
    int wm = (wave >> 1) * 64, wn = (wave & 1) * 64;
    int lr = lane & 15, kg = lane >> 4;
    f32x4 zero = {0.f, 0.f, 0.f, 0.f};
    f32x4 acc[4][4];
    for (int i = 0; i < 4; ++i)
        for (int j = 0; j < 4; ++j) acc[i][j] = zero;

    const unsigned short* Ap[3] = {Ahi, Ahi, Alo};
    const unsigned short* Wp[3] = {Whi, Wlo, Whi};

    #pragma unroll 1
    for (int p = 0; p < NPASS; ++p) {
        const unsigned short* A = Ap[p];
        const unsigned short* W = Wp[p];
        #pragma unroll 1
        for (int kt = 0; kt < K; kt += 64) {
            uint4 ar[4], br[4];
            #pragma unroll
            for (int q = 0; q < 4; ++q) {
                int c = q * 256 + tid, r = c >> 3, kc = c & 7;
                ar[q] = *(const uint4*)(A + (size_t)(m0 + r) * K + kt + kc * 8);
                br[q] = *(const uint4*)(W + (size_t)(n0 + r) * K + kt + kc * 8);
            }
            __syncthreads();
            #pragma unroll
            for (int q = 0; q < 4; ++q) {
                int c = q * 256 + tid, r = c >> 3, kc = c & 7;
                *(uint4*)&As[r][kc * 8] = ar[q];
                *(uint4*)&Bs[r][kc * 8] = br[q];
            }
            __syncthreads();
            #pragma unroll
            for (int kk = 0; kk < 2; ++kk) {
                bf16x8 af[4], bfr[4];
                #pragma unroll
                for (int i = 0; i < 4; ++i) af[i]  = *(const bf16x8*)&As[wm + i * 16 + lr][kk * 32 + kg * 8];
                #pragma unroll
                for (int j = 0; j < 4; ++j) bfr[j] = *(const bf16x8*)&Bs[wn + j * 16 + lr][kk * 32 + kg * 8];
                #pragma unroll
                for (int i = 0; i < 4; ++i)
                    #pragma unroll
                    for (int j = 0; j < 4; ++j)
                        acc[i][j] = __builtin_amdgcn_mfma_f32_16x16x32_bf16(af[i], bfr[j], acc[i][j], 0, 0, 0);
            }
        }
    }
    #pragma unroll
    for (int i = 0; i < 4; ++i) {
        int crow = m0 + wm + i * 16 + kg * 4;
        #pragma unroll
        for (int j = 0; j < 4; ++j) {
            int ccol = n0 + wn + j * 16 + lr;
            float bb = bias ? bias[ccol] : 0.0f;
            #pragma unroll
            for (int r = 0; r < 4; ++r)
                C[(size_t)(crow + r) * N + ccol] = acc[i][j][r] + bb;
        }
    }
}

// ---------------- row LayerNorm in-place: P[4096][2048], apply g,b ----------------
__global__ __launch_bounds__(256) void ln_rows_k(float* __restrict__ P,
                                                 const float* __restrict__ g,
                                                 const float* __restrict__ b) {
    int row = blockIdx.x, tid = threadIdx.x;
    float* p = P + (size_t)row * GATES;
    float4 v0 = ((const float4*)p)[tid];
    float4 v1 = ((const float4*)p)[tid + 256];
    float s  = v0.x + v0.y + v0.z + v0.w + v1.x + v1.y + v1.z + v1.w;
    float sq = v0.x*v0.x + v0.y*v0.y + v0.z*v0.z + v0.w*v0.w
             + v1.x*v1.x + v1.y*v1.y + v1.z*v1.z + v1.w*v1.w;
    __shared__ float rs[256], rq[256];
    rs[tid] = s; rq[tid] = sq; __syncthreads();
    for (int off = 128; off > 0; off >>= 1) {
        if (tid < off) { rs[tid] += rs[tid + off]; rq[tid] += rq[tid + off]; }
        __syncthreads();
    }
    float mean = rs[0] * (1.0f / GATES);
    float var  = rq[0] * (1.0f / GATES) - mean * mean;
    float inv  = rsqrtf(var + 1e-5f);
    float4 g0 = ((const float4*)g)[tid], g1 = ((const float4*)g)[tid + 256];
    float4 b0 = ((const float4*)b)[tid], b1 = ((const float4*)b)[tid + 256];
    float4 o0, o1;
    o0.x = (v0.x - mean) * inv * g0.x + b0.x;
    o0.y = (v0.y - mean) * inv * g0.y + b0.y;
    o0.z = (v0.z - mean) * inv * g0.z + b0.z;
    o0.w = (v0.w - mean) * inv * g0.w + b0.w;
    o1.x = (v1.x - mean) * inv * g1.x + b1.x;
    o1.y = (v1.y - mean) * inv * g1.y + b1.y;
    o1.z = (v1.z - mean) * inv * g1.z + b1.z;
    o1.w = (v1.w - mean) * inv * g1.w + b1.w;
    ((float4*)p)[tid] = o0;
    ((float4*)p)[tid + 256] = o1;
}

// ---------------- fence-free flag barrier: monotonic tags, coherent flag ops ----------------
// flags: NWG slots, 256B apart. Wave 0 polls all 64 flags (one per lane). No atomics, no
// cache-wide fences: payload moved via sc0/sc1 ops, so L2 contents stay valid & warm.
__device__ __forceinline__ void flag_sync(unsigned* flags, int w, unsigned tag) {
    asm volatile("s_waitcnt vmcnt(0)" ::: "memory");   // this thread's coh stores at LLC
    __syncthreads();                                   // all threads' stores drained
    if (threadIdx.x < 64) {
        if (threadIdx.x == 0) st_coh_u32(flags + (size_t)w * 64, tag);
        const unsigned* fp = flags + (size_t)threadIdx.x * 64;
        unsigned v;
        do {
            asm volatile("s_sleep 1");
            asm volatile("global_load_dword %0, %1, off sc0 sc1\n\ts_waitcnt vmcnt(0)"
                         : "=v"(v) : "v"(fp) : "memory");
        } while (__any(v < tag));
    }
    __syncthreads();
}

// ---------------- persistent LayerNorm-LSTM recurrence (one layer, all 128 steps)
// 64 WGs x 256 threads. WG w: phase A owns gate rows [w*32,w*32+32) as 3-term bf16 in LDS;
// phase B (w<32) owns batch element w (c-state in LDS). 6-pass split-MFMA z == f32 precision.
// All cross-WG payload (h state, zbuf, pstats) via coherent sc0/sc1 ops; no cache fences.
__global__ __launch_bounds__(256, 1) void lstm_persist_k(
        const float* __restrict__ Whh,       // [2048][512] (layer slice, f32)
        const float* __restrict__ gh, const float* __restrict__ bh,
        const float* __restrict__ gc, const float* __restrict__ bc,
        const float* __restrict__ LNi,       // [4096][2048] precomputed LN(x@Wi^T)
        unsigned short* __restrict__ hHi,    // [32][512] 3-term bf16 h state (init 0)
        unsigned short* __restrict__ hMid,
        unsigned short* __restrict__ hLo,
        float* __restrict__ zbuf,            // [32][2048]
        float* __restrict__ pstats,          // [64 wg][32 b][2]
        unsigned* __restrict__ flags,        // [64] x 64-uint stride
        unsigned short* __restrict__ seqHi,  // [4096][512]
        unsigned short* __restrict__ seqLo,  // nullable
        float* __restrict__ outH,            // [32][512] final h (f32)
        float* __restrict__ outC) {          // [32][512] final c (f32)
    __shared__ __align__(16) unsigned short Wlds[3][WROWS * HID];  // 96 KB
    __shared__ float ghs[GATES], bhs[GATES];                       // 16 KB
    __shared__ float gcs[HID], bcs[HID];                           // 4 KB
    __shared__ float c_lds[HID];                                   // 2 KB
    __shared__ float pstatA[2][BATCH][2];
    __shared__ float sred[2];
    __shared__ float cred[4][2];

    const int w = blockIdx.x;
    const int tid = threadIdx.x;
    const int wave = tid >> 6, lane = tid & 63;
    const int lr = lane & 15, kg = lane >> 4;
    const int mr = wave >> 1, nc = wave & 1;

    for (int u = tid; u < GATES; u += 256) { ghs[u] = gh[u]; bhs[u] = bh[u]; }
    for (int u = tid; u < HID;   u += 256) { gcs[u] = gc[u]; bcs[u] = bc[u]; c_lds[u] = 0.f; }

    // ---- stage Whh rows [w*32, w*32+32) -> 3-term bf16, XOR-swizzled 16B chunks ----
    #pragma unroll
    for (int i = 0; i < 8; ++i) {
        int chunk = tid + i * 256;            // 0..2047 : row r (0..31), 8-elem chunk c8 (0..63)
        int r = chunk >> 6, c8 = chunk & 63;
        const float* src = Whh + (size_t)(w * WROWS + r) * HID + c8 * 8;
        float4 v0 = *(const float4*)(src);
        float4 v1 = *(const float4*)(src + 4);
        float f[8] = {v0.x, v0.y, v0.z, v0.w, v1.x, v1.y, v1.z, v1.w};
        bf16x8 t0, t1, t2;
        #pragma unroll
        for (int e = 0; e < 8; ++e) {
            unsigned short h0 = f2bf(f[e]);
            float r1 = f[e] - bf2f(h0);
            unsigned short h1 = f2bf(r1);
            float r2 = r1 - bf2f(h1);
            t0[e] = (short)h0; t1[e] = (short)h1; t2[e] = (short)f2bf(r2);
        }
        int eoff = r * HID + ((c8 * 8) ^ ((r & 7) * 8));
        *(bf16x8*)&Wlds[0][eoff] = t0;
        *(bf16x8*)&Wlds[1][eoff] = t1;
        *(bf16x8*)&Wlds[2][eoff] = t2;
    }
    __syncthreads();

    const int arow = (mr * 16 + lr) * HID;
    const int wrow = (nc * 16 + lr) * HID;
    const int sw = (lr & 7) * 8;
    const unsigned short* const hsrc[3] = {hHi, hMid, hLo};

    for (int t = 0; t < S_LEN; ++t) {
        // ===== Phase A: z[b][w*32+j] = h @ W_slice^T, 6-pass 3-term split bf16 =====
        // term-set s holds its 16 A-fragments in regs, reused across (3,2,1) W-term passes
        f32x4 zero = {0.f, 0.f, 0.f, 0.f};
        f32x4 acc[4] = {zero, zero, zero, zero};
        uint4 hf[16];
        #pragma unroll
        for (int s = 0; s < 3; ++s) {
            const unsigned short* hp = hsrc[s] + arow;
            #pragma unroll
            for (int kk = 0; kk < 16; ++kk) {
                const void* p = hp + kk * 32 + kg * 8;
                asm volatile("global_load_dwordx4 %0, %1, off sc0 sc1"
                             : "=v"(hf[kk]) : "v"(p) : "memory");
            }
            asm volatile("s_waitcnt vmcnt(0)" ::: "memory");
            __builtin_amdgcn_sched_barrier(0);
            const int nuse = (s == 0) ? 3 : (s == 1) ? 2 : 1;
            #pragma unroll
            for (int p = 0; p < 3; ++p) {
                if (p < nuse) {
                    #pragma unroll
                    for (int kk = 0; kk < 16; ++kk) {
                        bf16x8 bv = *(const bf16x8*)&Wlds[p][wrow + ((kk * 32 + kg * 8) ^ sw)];
                        bf16x8 av = __builtin_bit_cast(bf16x8, hf[kk]);
                        acc[kk & 3] = __builtin_amdgcn_mfma_f32_16x16x32_bf16(av, bv, acc[kk & 3], 0, 0, 0);
                    }
                }
            }
        }
        f32x4 a = acc[0] + acc[1] + acc[2] + acc[3];

        float sv[4], qv[4];
        #pragma unroll
        for (int r = 0; r < 4; ++r) {
            int b = mr * 16 + kg * 4 + r;
            int col = w * WROWS + nc * 16 + lr;
            st_coh_f32(&zbuf[b * GATES + col], a[r]);
            sv[r] = a[r]; qv[r] = a[r] * a[r];
        }
        #pragma unroll
        for (int m = 1; m <= 8; m <<= 1) {
            #pragma unroll
            for (int r = 0; r < 4; ++r) {
                sv[r] += __shfl_xor(sv[r], m);
                qv[r] += __shfl_xor(qv[r], m);
            }
        }
        if (lr == 0) {
            #pragma unroll
            for (int r = 0; r < 4; ++r) {
                int b = mr * 16 + kg * 4 + r;
                pstatA[nc][b][0] = sv[r];
                pstatA[nc][b][1] = qv[r];
            }
        }
        __syncthreads();
        if (tid < 64) {
            int b = tid & 31, s = tid >> 5;
            st_coh_f32(&pstats[(w * BATCH + b) * 2 + s], pstatA[0][b][s] + pstatA[1][b][s]);
        }
        flag_sync(flags, w, 2u * t + 1u);    // z + stats visible

        // ===== Phase B: batch element g = w (first 32 WGs) =====
        if (w < BATCH) {
            const int g = w;
            const int row = t * BATCH + g;
            if (tid < 128) {
                int s = tid >> 6, ww = tid & 63;
                const void* p = &pstats[(ww * BATCH + g) * 2 + s];
                float v;
                asm volatile("global_load_dword %0, %1, off sc0 sc1\n\ts_waitcnt vmcnt(0)"
                             : "=v"(v) : "v"(p) : "memory");
                #pragma unroll
                for (int m = 1; m <= 32; m <<= 1) v += __shfl_xor(v, m);
                if ((tid & 63) == 0) sred[s] = v;
            }
            __syncthreads();
            float mean = sred[0] * (1.0f / GATES);
            float var  = sred[1] * (1.0f / GATES) - mean * mean;
            float inv  = rsqrtf(var + 1e-5f);

            const float* lrow = LNi + (size_t)row * GATES;
            const float* zrow = zbuf + g * GATES;
            float zv[8];
            #pragma unroll
            for (int q = 0; q < 2; ++q) {
                int u = tid + q * 256;
                #pragma unroll
                for (int part = 0; part < 4; ++part) {
                    const void* p = &zrow[u + part * 512];
                    asm volatile("global_load_dword %0, %1, off sc0 sc1"
                                 : "=v"(zv[q * 4 + part]) : "v"(p) : "memory");
                }
            }
            asm volatile("s_waitcnt vmcnt(0)" ::: "memory");
            __builtin_amdgcn_sched_barrier(0);

            float cvals[2], ovals[2];
            float cs = 0.f, cq = 0.f;
            #pragma unroll
            for (int q = 0; q < 2; ++q) {
                int u = tid + q * 256;
                float gi_ = (zv[q*4+0] - mean) * inv * ghs[u       ] + bhs[u       ] + lrow[u       ];
                float gf_ = (zv[q*4+1] - mean) * inv * ghs[u + 512 ] + bhs[u + 512 ] + lrow[u + 512 ];
                float gg_ = (zv[q*4+2] - mean) * inv * ghs[u + 1024] + bhs[u + 1024] + lrow[u + 1024];
                float go_ = (zv[q*4+3] - mean) * inv * ghs[u + 1536] + bhs[u + 1536] + lrow[u + 1536];
                float c = sigmoidf_(gf_) * c_lds[u] + sigmoidf_(gi_) * tanhf(gg_);
                c_lds[u] = c;
                cvals[q] = c; ovals[q] = go_;
                cs += c; cq += c * c;
            }
            #pragma unroll
            for (int m = 1; m < 64; m <<= 1) { cs += __shfl_xor(cs, m); cq += __shfl_xor(cq, m); }
            if (lane == 0) { cred[wave][0] = cs; cred[wave][1] = cq; }
            __syncthreads();
            float csum = cred[0][0] + cred[1][0] + cred[2][0] + cred[3][0];
            float cqsum = cred[0][1] + cred[1][1] + cred[2][1] + cred[3][1];
            float meanc = csum * (1.0f / HID);
            float varc  = cqsum * (1.0f / HID) - meanc * meanc;
            float invc  = rsqrtf(varc + 1e-5f);
            #pragma unroll
            for (int q = 0; q < 2; ++q) {
                int u = tid + q * 256;
                float h = sigmoidf_(ovals[q]) * tanhf((cvals[q] - meanc) * invc * gcs[u] + bcs[u]);
                unsigned short h0 = f2bf(h);
                float r1 = h - bf2f(h0);
                unsigned short h1 = f2bf(r1);
                unsigned short h2 = f2bf(r1 - bf2f(h1));
                st_coh_u16(&hHi [g * HID + u], h0);
                st_coh_u16(&hMid[g * HID + u], h1);
                st_coh_u16(&hLo [g * HID + u], h2);
                seqHi[(size_t)row * HID + u] = h0;            // normal store: consumed post-kernel
                if (seqLo) seqLo[(size_t)row * HID + u] = h1;
                if (t == S_LEN - 1) { outH[g * HID + u] = h; outC[g * HID + u] = cvals[q]; }
            }
        }
        if (t < S_LEN - 1) flag_sync(flags, w, 2u * t + 2u);   // h visible for next step
    }
}

// ---------------- in-place log-softmax over V, per row ----------------
__global__ __launch_bounds__(256) void logsoftmax_k(float* __restrict__ out) {
    int row = blockIdx.x, tid = threadIdx.x;
    float* p = out + (size_t)row * VOCAB;
    const float4* p4 = (const float4*)p;
    float m = -3.4e38f, s = 0.f;
    for (int j = tid; j < VOCAB / 4; j += 256) {
        float4 v = p4[j];
        float xs[4] = {v.x, v.y, v.z, v.w};
        #pragma unroll
        for (int e = 0; e < 4; ++e) {
            float x = xs[e];
            if (x > m) { s *= __expf(m - x); m = x; }
            s += __expf(x - m);
        }
    }
    __shared__ float rm[256], rv[256];
    rm[tid] = m; rv[tid] = s; __syncthreads();
    for (int off = 128; off > 0; off >>= 1) {
        if (tid < off) {
            float ma = rm[tid], mb = rm[tid + off];
            float M = fmaxf(ma, mb);
            rv[tid] = rv[tid] * __expf(ma - M) + rv[tid + off] * __expf(mb - M);
            rm[tid] = M;
        }
        __syncthreads();
    }
    float logZ = rm[0] + __logf(rv[0]);
    for (int j = tid; j < VOCAB / 4; j += 256) {
        float4 v = p4[j];
        v.x -= logZ; v.y -= logZ; v.z -= logZ; v.w -= logZ;
        ((float4*)p)[j] = v;
    }
}

extern "C" void kernel_launch(void* const* d_in, const int* in_sizes, int n_in,
                              void* d_out, int out_size, void* d_ws, size_t ws_size,
                              hipStream_t stream) {
    const int*   tokens = (const int*)d_in[0];
    const float* emb    = (const float*)d_in[1];
    const float* W_ih   = (const float*)d_in[2];
    const float* W_hh   = (const float*)d_in[3];
    const float* g_ih   = (const float*)d_in[4];
    const float* b_ih   = (const float*)d_in[5];
    const float* g_hh   = (const float*)d_in[6];
    const float* b_hh   = (const float*)d_in[7];
    const float* g_c    = (const float*)d_in[8];
    const float* b_c    = (const float*)d_in[9];
    const float* W_fc   = (const float*)d_in[10];
    const float* b_fc   = (const float*)d_in[11];
    float* out = (float*)d_out;

    char* ws = (char*)d_ws;
    unsigned short* XembHi  = (unsigned short*)(ws + 0);               //  4 MB
    unsigned short* XembLo  = (unsigned short*)(ws + ( 4ull << 20));   //  4 MB
    unsigned short* hseq0Hi = (unsigned short*)(ws + ( 8ull << 20));   //  4 MB
    unsigned short* hseq0Lo = (unsigned short*)(ws + (12ull << 20));   //  4 MB
    unsigned short* hseq1Hi = (unsigned short*)(ws + (16ull << 20));   //  4 MB
    unsigned short* WihHi   = (unsigned short*)(ws + (20ull << 20));   //  2 MB
    unsigned short* WihLo   = (unsigned short*)(ws + (22ull << 20));   //  2 MB
    unsigned short* WfcHi   = (unsigned short*)(ws + (24ull << 20));   // 32.8 MB
    float*          P       = (float*)(ws + (58ull << 20));            // 32 MB
    char*           xtra    = ws + (90ull << 20);
    float*          zbuf    = (float*)(xtra);                                      // 256 KB
    float*          pstats  = (float*)(xtra + 262144);                             // 16 KB
    unsigned short* hHi     = (unsigned short*)(xtra + 262144 + 16384);            // 32 KB
    unsigned short* hMid    = (unsigned short*)(xtra + 262144 + 16384 + 32768);    // 32 KB
    unsigned short* hLo     = (unsigned short*)(xtra + 262144 + 16384 + 65536);    // 32 KB
    unsigned*       flags   = (unsigned*)(xtra + 262144 + 16384 + 98304);          // 16 KB

    float* tail = out + (size_t)NROWS * VOCAB;   // h_n [2][32][512] then c_n [2][32][512]

    embed_k<<<2048, 256, 0, stream>>>(tokens, emb, XembHi, XembLo);

    const unsigned short* xhi[2] = {XembHi, hseq0Hi};
    const unsigned short* xlo[2] = {XembLo, hseq0Lo};
    unsigned short* shi[2] = {hseq0Hi, hseq1Hi};
    unsigned short* slo[2] = {hseq0Lo, nullptr};

    for (int l = 0; l < 2; ++l) {
        f32_split_k<<<1024, 256, 0, stream>>>(W_ih + (size_t)l * GATES * HID, WihHi, WihLo, GATES * HID / 4);
        gemm_split<3><<<dim3(GATES / 128, NROWS / 128), 256, 0, stream>>>(
            xhi[l], xlo[l], WihHi, WihLo, nullptr, P, NROWS, GATES);
        ln_rows_k<<<NROWS, 256, 0, stream>>>(P, g_ih + l * GATES, b_ih + l * GATES);
        hipMemsetAsync(hHi,  0, BATCH * HID * sizeof(unsigned short), stream);
        hipMemsetAsync(hMid, 0, BATCH * HID * sizeof(unsigned short), stream);
        hipMemsetAsync(hLo,  0, BATCH * HID * sizeof(unsigned short), stream);
        hipMemsetAsync(flags, 0, NWG * 64 * sizeof(unsigned), stream);
        lstm_persist_k<<<NWG, 256, 0, stream>>>(
            W_hh + (size_t)l * GATES * HID,
            g_hh + l * GATES, b_hh + l * GATES,
            g_c + l * HID, b_c + l * HID,
            P, hHi, hMid, hLo, zbuf, pstats, flags,
            shi[l], slo[l],
            tail + l * BATCH * HID,
            tail + 2 * BATCH * HID + l * BATCH * HID);
    }

    f32_split_k<<<16000, 256, 0, stream>>>(W_fc, WfcHi, nullptr, VOCAB * HID / 4);
    gemm_split<1><<<dim3(VOCAB / 128, NROWS / 128), 256, 0, stream>>>(
        hseq1Hi, nullptr, WfcHi, nullptr, b_fc, out, NROWS, VOCAB);
    logsoftmax_k<<<NROWS, 256, 0, stream>>>(out);
}